// Round 16
// baseline (121.600 us; speedup 1.0000x reference)
//
#include <hip/hip_runtime.h>
#include <hip/hip_bf16.h>
#include <cstdint>
#include <cstddef>

typedef __attribute__((ext_vector_type(8))) short short8_t;
typedef __attribute__((ext_vector_type(4))) float f32x4;

__device__ __forceinline__ void gload16(const void* g, void* l) {
  __builtin_amdgcn_global_load_lds(
      (const __attribute__((address_space(1))) void*)g,
      (__attribute__((address_space(3))) void*)l, 16, 0, 0);
}

#define BARRIER() do { asm volatile("" ::: "memory"); __builtin_amdgcn_s_barrier(); asm volatile("" ::: "memory"); } while (0)
#define LGKM0 asm volatile("s_waitcnt lgkmcnt(0)" ::: "memory")
#define WVM(n) asm volatile("s_waitcnt vmcnt(" #n ")" ::: "memory")

// -------- fused preproc: cvt x->bf16 | transpose Win | transpose Wout --------
__global__ __launch_bounds__(256) void preproc_kernel(
    const float* __restrict__ x, __hip_bfloat16* __restrict__ xb,
    const float* __restrict__ Win, __hip_bfloat16* __restrict__ WinT,
    const float* __restrict__ Wout, __hip_bfloat16* __restrict__ WoutT) {
  __shared__ float tile[32][33];
  const int b = blockIdx.x;
  const int tid = threadIdx.x;
  if (b < 8192) {  // cvt: 8192x1024 f32 -> bf16, 4 elems/thread
    int idx = (b * 256 + tid) * 4;
    float4 v = *reinterpret_cast<const float4*>(x + idx);
    union { short4 s4; __hip_bfloat16 h[4]; } u;
    u.h[0] = __float2bfloat16(v.x);
    u.h[1] = __float2bfloat16(v.y);
    u.h[2] = __float2bfloat16(v.z);
    u.h[3] = __float2bfloat16(v.w);
    *reinterpret_cast<short4*>(xb + idx) = u.s4;
    return;
  }
  const float* in;  __hip_bfloat16* out;  int R, C, tb;
  if (b < 8192 + 2048) { tb = b - 8192;  in = Win;  out = WinT;  R = 1024; C = 2048; }
  else                 { tb = b - 10240; in = Wout; out = WoutT; R = 2048; C = 1024; }
  const int nbx = C / 32;
  const int c0 = (tb % nbx) * 32, r0 = (tb / nbx) * 32;
  const int tx = tid & 31, ty = tid >> 5;  // 32x8
#pragma unroll
  for (int j = 0; j < 32; j += 8)
    tile[ty + j][tx] = in[(size_t)(r0 + ty + j) * C + c0 + tx];
  __syncthreads();
#pragma unroll
  for (int j = 0; j < 32; j += 8)
    out[(size_t)(c0 + ty + j) * R + r0 + tx] = __float2bfloat16(tile[tx][ty + j]);
}

// ---------------- GEMM1: 256x256 4-phase/K-tile schedule (R9/R15 verbatim) -------
// C = silu(A[M,K] @ Bt[N,K]^T + bias) -> bf16.  512 thr (8 waves, 2M x 4N),
// per-wave 128x64 out. BK=64. Unit = [256 rows][32 K] bf16 = 16KB; LDS = 128KB.
__global__ __launch_bounds__(512, 1) void gemm8p4_kernel(
    const __hip_bfloat16* __restrict__ A,
    const __hip_bfloat16* __restrict__ Bt,
    const float* __restrict__ bias,
    __hip_bfloat16* __restrict__ Cout,
    int M, int N, int K) {
  constexpr int AUNIT = 16384;
  constexpr int BOFF = 4 * AUNIT;  // A region 64KB, B region 64KB
  __shared__ int4 ldsv[(8 * AUNIT) / 16];  // 128KB
  char* lds = (char*)ldsv;

  const int tid = threadIdx.x;
  const int l = tid & 63;
  const int w = tid >> 6;
  const int wm = w >> 2, wn = w & 3;         // 2(M) x 4(N); per-wave 128x64
  const int fr = l & 15;
  const int sl = ((l >> 4) ^ ((fr >> 3) << 1)) * 16;  // st_16x32 swizzled slot
  const int arowb = (wm * 128 + fr) * 64 + sl;        // byte in 16KB A unit
  const int browb = (wn * 64 + fr) * 64 + sl;         // byte in 16KB B unit

  const int nbn = N >> 8;
  int bid = blockIdx.x;
  const int cpx = gridDim.x >> 3;            // XCD chunking; grid % 8 == 0
  bid = (bid & 7) * cpx + (bid >> 3);
  const int brow = (bid / nbn) * 256;
  const int bcol = (bid % nbn) * 256;
  const size_t K2 = (size_t)K * 2;

  int ar[2], acb[2], dst[2];
#pragma unroll
  for (int j = 0; j < 2; ++j) {
    int d = j * 8192 + w * 1024 + l * 16;
    int lg = d ^ (((d >> 9) & 1) << 5);
    ar[j] = lg >> 6;  acb[j] = lg & 63;
    dst[j] = j * 8192 + w * 1024;
  }

  const char* Abp = (const char*)A;
  const char* Bbp = (const char*)Bt;

  auto stA = [&](int t, int kk) {
    const int base = ((t & 1) * 2 + kk) * AUNIT;
#pragma unroll
    for (int j = 0; j < 2; ++j)
      gload16(Abp + (size_t)(brow + ar[j]) * K2 + (size_t)t * 128 + kk * 64 + acb[j],
              lds + base + dst[j]);
  };
  auto stB = [&](int t, int kk) {
    const int base = BOFF + ((t & 1) * 2 + kk) * AUNIT;
#pragma unroll
    for (int j = 0; j < 2; ++j)
      gload16(Bbp + (size_t)(bcol + ar[j]) * K2 + (size_t)t * 128 + kk * 64 + acb[j],
              lds + base + dst[j]);
  };

  f32x4 acc[8][4];
#pragma unroll
  for (int m = 0; m < 8; ++m)
#pragma unroll
    for (int n = 0; n < 4; ++n) acc[m][n] = (f32x4)0.f;

  short8_t af[4], bf[4];
  auto rdA4 = [&](int t, int kk, int mh) {
    const int base = ((t & 1) * 2 + kk) * AUNIT + arowb + mh * 4096;
#pragma unroll
    for (int j = 0; j < 4; ++j)
      af[j] = *(const short8_t*)(lds + base + j * 1024);
  };
  auto rdB4 = [&](int t, int kk) {
    const int base = BOFF + ((t & 1) * 2 + kk) * AUNIT + browb;
#pragma unroll
    for (int j = 0; j < 4; ++j)
      bf[j] = *(const short8_t*)(lds + base + j * 1024);
  };
  auto mm0 = [&]() {
    __builtin_amdgcn_s_setprio(1);
#pragma unroll
    for (int j = 0; j < 4; ++j)
#pragma unroll
      for (int n = 0; n < 4; ++n)
        acc[j][n] = __builtin_amdgcn_mfma_f32_16x16x32_bf16(af[j], bf[n], acc[j][n], 0, 0, 0);
    __builtin_amdgcn_s_setprio(0);
  };
  auto mm1 = [&]() {
    __builtin_amdgcn_s_setprio(1);
#pragma unroll
    for (int j = 0; j < 4; ++j)
#pragma unroll
      for (int n = 0; n < 4; ++n)
        acc[4 + j][n] = __builtin_amdgcn_mfma_f32_16x16x32_bf16(af[j], bf[n], acc[4 + j][n], 0, 0, 0);
    __builtin_amdgcn_s_setprio(0);
  };

  const int NT = K >> 6;  // BK=64; NT >= 3
  stA(0, 0); stB(0, 0); stA(0, 1); stB(0, 1); stA(1, 0); stB(1, 0);
  WVM(8); BARRIER();

  for (int T = 0; T < NT - 2; ++T) {
    rdA4(T, 0, 0); rdB4(T, 0); stA(T + 1, 1);
    BARRIER(); LGKM0; mm0(); BARRIER();
    rdA4(T, 0, 1);             stB(T + 1, 1);
    BARRIER(); LGKM0; mm1(); WVM(8); BARRIER();
    rdA4(T, 1, 0); rdB4(T, 1); stA(T + 2, 0);
    BARRIER(); LGKM0; mm0(); BARRIER();
    rdA4(T, 1, 1);             stB(T + 2, 0);
    BARRIER(); LGKM0; mm1(); WVM(8); BARRIER();
  }
  {
    const int T = NT - 2;
    rdA4(T, 0, 0); rdB4(T, 0); stA(T + 1, 1);
    BARRIER(); LGKM0; mm0(); BARRIER();
    rdA4(T, 0, 1);             stB(T + 1, 1);
    BARRIER(); LGKM0; mm1(); WVM(8); BARRIER();
    rdA4(T, 1, 0); rdB4(T, 1);
    BARRIER(); LGKM0; mm0(); BARRIER();
    rdA4(T, 1, 1);
    BARRIER(); LGKM0; mm1(); WVM(4); BARRIER();
  }
  {
    const int T = NT - 1;
    rdA4(T, 0, 0); rdB4(T, 0);
    BARRIER(); LGKM0; mm0(); BARRIER();
    rdA4(T, 0, 1);
    BARRIER(); LGKM0; mm1(); WVM(0); BARRIER();
    rdA4(T, 1, 0); rdB4(T, 1);
    BARRIER(); LGKM0; mm0(); BARRIER();
    rdA4(T, 1, 1);
    BARRIER(); LGKM0; mm1();
  }

  const int r0 = brow + wm * 128 + (l >> 4) * 4;
  const int c0 = bcol + wn * 64 + fr;
#pragma unroll
  for (int m = 0; m < 8; ++m) {
#pragma unroll
    for (int n = 0; n < 4; ++n) {
      const int col = c0 + n * 16;
      const float bv = bias[col];
#pragma unroll
      for (int j = 0; j < 4; ++j) {
        const int row = r0 + m * 16 + j;
        float v = acc[m][n][j] + bv;
        v = v / (1.0f + __expf(-v));
        Cout[(size_t)row * N + col] = __float2bfloat16(v);
      }
    }
  }
}

// ---------------- GEMM2: 256x128 4-phase port of gemm8p4 (f32 out) ----------
// Same phase table as gemm8p4; B unit = [128 rows][32 K] = 8KB (stB = 1 gload).
// Per-wave out 128x32 (acc[8][2], 8 MFMA/phase). LDS = 4x16KB + 4x8KB = 96KB.
// vmcnt ledger (2A+1B mix): steady WVM(6) at ph1/ph3 ends (younger set =
// 2+1+2+1), prologue WVM(6), tail 6 -> 3 -> 0. Slot parity as gemm8p4.
__global__ __launch_bounds__(512, 1) void gemm8p4n_kernel(
    const __hip_bfloat16* __restrict__ A,
    const __hip_bfloat16* __restrict__ Bt,
    const float* __restrict__ bias,
    float* __restrict__ Cout,
    int M, int N, int K) {
  constexpr int AUNIT = 16384, BUNIT = 8192;
  constexpr int BOFF = 4 * AUNIT;  // A region 64KB, B region 32KB
  __shared__ int4 ldsv[(4 * AUNIT + 4 * BUNIT) / 16];  // 96KB
  char* lds = (char*)ldsv;

  const int tid = threadIdx.x;
  const int l = tid & 63;
  const int w = tid >> 6;
  const int wm = w >> 2, wn = w & 3;         // 2(M) x 4(N); per-wave 128x32
  const int fr = l & 15;
  const int sl = ((l >> 4) ^ ((fr >> 3) << 1)) * 16;  // st_16x32 swizzled slot
  const int arowb = (wm * 128 + fr) * 64 + sl;        // byte in 16KB A unit
  const int browb = (wn * 32 + fr) * 64 + sl;         // byte in 8KB B unit

  const int nbn = N >> 7;
  int bid = blockIdx.x;
  const int cpx = gridDim.x >> 3;            // XCD chunking; grid % 8 == 0
  bid = (bid & 7) * cpx + (bid >> 3);
  const int brow = (bid / nbn) * 256;
  const int bcol = (bid % nbn) * 128;
  const size_t K2 = (size_t)K * 2;

  int ar[2], acb[2], dst[2];
#pragma unroll
  for (int j = 0; j < 2; ++j) {
    int d = j * 8192 + w * 1024 + l * 16;
    int lg = d ^ (((d >> 9) & 1) << 5);
    ar[j] = lg >> 6;  acb[j] = lg & 63;
    dst[j] = j * 8192 + w * 1024;
  }

  const char* Abp = (const char*)A;
  const char* Bbp = (const char*)Bt;

  auto stA = [&](int t, int kk) {
    const int base = ((t & 1) * 2 + kk) * AUNIT;
#pragma unroll
    for (int j = 0; j < 2; ++j)
      gload16(Abp + (size_t)(brow + ar[j]) * K2 + (size_t)t * 128 + kk * 64 + acb[j],
              lds + base + dst[j]);
  };
  auto stB = [&](int t, int kk) {  // 1 gload (8KB unit)
    const int base = BOFF + ((t & 1) * 2 + kk) * BUNIT;
    gload16(Bbp + (size_t)(bcol + ar[0]) * K2 + (size_t)t * 128 + kk * 64 + acb[0],
            lds + base + dst[0]);
  };

  f32x4 acc[8][2];
#pragma unroll
  for (int m = 0; m < 8; ++m)
#pragma unroll
    for (int n = 0; n < 2; ++n) acc[m][n] = (f32x4)0.f;

  short8_t af[4], bf[2];
  auto rdA4 = [&](int t, int kk, int mh) {
    const int base = ((t & 1) * 2 + kk) * AUNIT + arowb + mh * 4096;
#pragma unroll
    for (int j = 0; j < 4; ++j)
      af[j] = *(const short8_t*)(lds + base + j * 1024);
  };
  auto rdB2 = [&](int t, int kk) {
    const int base = BOFF + ((t & 1) * 2 + kk) * BUNIT + browb;
#pragma unroll
    for (int j = 0; j < 2; ++j)
      bf[j] = *(const short8_t*)(lds + base + j * 1024);
  };
  auto mm0 = [&]() {
    __builtin_amdgcn_s_setprio(1);
#pragma unroll
    for (int j = 0; j < 4; ++j)
#pragma unroll
      for (int n = 0; n < 2; ++n)
        acc[j][n] = __builtin_amdgcn_mfma_f32_16x16x32_bf16(af[j], bf[n], acc[j][n], 0, 0, 0);
    __builtin_amdgcn_s_setprio(0);
  };
  auto mm1 = [&]() {
    __builtin_amdgcn_s_setprio(1);
#pragma unroll
    for (int j = 0; j < 4; ++j)
#pragma unroll
      for (int n = 0; n < 2; ++n)
        acc[4 + j][n] = __builtin_amdgcn_mfma_f32_16x16x32_bf16(af[j], bf[n], acc[4 + j][n], 0, 0, 0);
    __builtin_amdgcn_s_setprio(0);
  };

  const int NT = K >> 6;  // BK=64; NT >= 3
  stA(0, 0); stB(0, 0); stA(0, 1); stB(0, 1); stA(1, 0); stB(1, 0);
  WVM(6); BARRIER();

  for (int T = 0; T < NT - 2; ++T) {
    rdA4(T, 0, 0); rdB2(T, 0); stA(T + 1, 1);
    BARRIER(); LGKM0; mm0(); BARRIER();
    rdA4(T, 0, 1);             stB(T + 1, 1);
    BARRIER(); LGKM0; mm1(); WVM(6); BARRIER();
    rdA4(T, 1, 0); rdB2(T, 1); stA(T + 2, 0);
    BARRIER(); LGKM0; mm0(); BARRIER();
    rdA4(T, 1, 1);             stB(T + 2, 0);
    BARRIER(); LGKM0; mm1(); WVM(6); BARRIER();
  }
  {
    const int T = NT - 2;
    rdA4(T, 0, 0); rdB2(T, 0); stA(T + 1, 1);
    BARRIER(); LGKM0; mm0(); BARRIER();
    rdA4(T, 0, 1);             stB(T + 1, 1);
    BARRIER(); LGKM0; mm1(); WVM(6); BARRIER();
    rdA4(T, 1, 0); rdB2(T, 1);
    BARRIER(); LGKM0; mm0(); BARRIER();
    rdA4(T, 1, 1);
    BARRIER(); LGKM0; mm1(); WVM(3); BARRIER();
  }
  {
    const int T = NT - 1;
    rdA4(T, 0, 0); rdB2(T, 0);
    BARRIER(); LGKM0; mm0(); BARRIER();
    rdA4(T, 0, 1);
    BARRIER(); LGKM0; mm1(); WVM(0); BARRIER();
    rdA4(T, 1, 0); rdB2(T, 1);
    BARRIER(); LGKM0; mm0(); BARRIER();
    rdA4(T, 1, 1);
    BARRIER(); LGKM0; mm1();
  }

  // epilogue: C/D layout col = lane&15, row = (lane>>4)*4 + reg; f32 out
  const int r0 = brow + wm * 128 + (l >> 4) * 4;
  const int c0 = bcol + wn * 32 + fr;
#pragma unroll
  for (int m = 0; m < 8; ++m) {
#pragma unroll
    for (int n = 0; n < 2; ++n) {
      const int col = c0 + n * 16;
      const float bv = bias[col];
#pragma unroll
      for (int j = 0; j < 4; ++j) {
        const int row = r0 + m * 16 + j;
        Cout[(size_t)row * N + col] = acc[m][n][j] + bv;
      }
    }
  }
}

// ---------------- EMA scan: y = cb_i * g + Dp_i * xi ----------------
__global__ __launch_bounds__(256) void scan_kernel(
    const __hip_bfloat16* __restrict__ xi,  // [B*L, DI]
    const float* __restrict__ Bp,           // [DI, DS]
    const float* __restrict__ Cp,           // [DS, DI]
    const float* __restrict__ Dp,           // [DI]
    __hip_bfloat16* __restrict__ y) {
  constexpr int L = 2048, DI = 2048, DS = 16, TW = 256, H = 32;
  const int tid = threadIdx.x;
  const int bidx = blockIdx.x;
  const int iblk = bidx & 7;
  const int chunk = (bidx >> 3) & 7;
  const int b = bidx >> 6;
  const int i = iblk * 256 + tid;

  float cb = 0.f;
#pragma unroll
  for (int s = 0; s < DS; ++s) cb += Bp[i * DS + s] * Cp[s * DI + i];
  const float dp = Dp[i];

  const int t0 = chunk * TW;
  int tstart = t0 - H;
  if (tstart < 0) tstart = 0;

  const __hip_bfloat16* xp = xi + (size_t)(b * L) * DI + i;
  __hip_bfloat16* yp = y + (size_t)(b * L) * DI + i;

  float g = 0.f;
  const __hip_bfloat16* p = xp + (size_t)tstart * DI;
  for (int t = tstart; t < t0; ++t, p += DI)
    g = g * 0.9f + __bfloat162float(*p);
  __hip_bfloat16* q = yp + (size_t)t0 * DI;
  for (int t = 0; t < TW; ++t, p += DI, q += DI) {
    float xv = __bfloat162float(*p);
    g = g * 0.9f + xv;
    *q = __float2bfloat16(cb * g + dp * xv);
  }
}

extern "C" void kernel_launch(void* const* d_in, const int* in_sizes, int n_in,
                              void* d_out, int out_size, void* d_ws, size_t ws_size,
                              hipStream_t stream) {
  const float* x    = (const float*)d_in[0];
  const float* Win  = (const float*)d_in[1];
  const float* bin  = (const float*)d_in[2];
  const float* Bp   = (const float*)d_in[3];
  const float* Cp   = (const float*)d_in[4];
  const float* Dp   = (const float*)d_in[5];
  const float* Wout = (const float*)d_in[6];
  const float* bout = (const float*)d_in[7];
  float* out = (float*)d_out;

  constexpr int Bb = 4, L = 2048, DM = 1024, DI = 2048;
  constexpr int Mrows = Bb * L;  // 8192

  char* ws = (char*)d_ws;
  __hip_bfloat16* xb    = (__hip_bfloat16*)ws;                           // 16 MB
  __hip_bfloat16* WinT  = (__hip_bfloat16*)(ws + (16u << 20));           // 4 MB
  __hip_bfloat16* WoutT = (__hip_bfloat16*)(ws + (20u << 20));           // 4 MB
  __hip_bfloat16* xi    = (__hip_bfloat16*)(ws + (24u << 20));           // 32 MB
  __hip_bfloat16* yb    = (__hip_bfloat16*)(ws + (56u << 20));           // 32 MB

  // 1. fused preproc: x->bf16 (8192 blocks) | Win^T (2048) | Wout^T (2048)
  preproc_kernel<<<8192 + 2048 + 2048, 256, 0, stream>>>(
      x, xb, Win, WinT, Wout, WoutT);
  // 2. xi = silu(xb @ WinT^T + bin)  [8192,2048] bf16. 256^2 tiles, grid 32x8=256.
  gemm8p4_kernel<<<(Mrows / 256) * (DI / 256), 512, 0, stream>>>(
      xb, WinT, bin, xi, Mrows, DI, DM);
  // 3. EMA scan -> y bf16
  scan_kernel<<<Bb * (L / 256) * (DI / 256), 256, 0, stream>>>(xi, Bp, Cp, Dp, yb);
  // 4. out = yb @ WoutT^T + bout  [8192,1024] f32. 256x128 4-phase, grid 32x8=256.
  gemm8p4n_kernel<<<(Mrows / 256) * (DM / 128), 512, 0, stream>>>(
      yb, WoutT, bout, out, Mrows, DM, DI);
}

// Round 17
// 116.799 us; speedup vs baseline: 1.0411x; 1.0411x over previous
//
#include <hip/hip_runtime.h>
#include <hip/hip_bf16.h>
#include <cstdint>
#include <cstddef>

typedef __attribute__((ext_vector_type(8))) short short8_t;
typedef __attribute__((ext_vector_type(4))) float f32x4;

__device__ __forceinline__ void gload16(const void* g, void* l) {
  __builtin_amdgcn_global_load_lds(
      (const __attribute__((address_space(1))) void*)g,
      (__attribute__((address_space(3))) void*)l, 16, 0, 0);
}

#define BARRIER() do { asm volatile("" ::: "memory"); __builtin_amdgcn_s_barrier(); asm volatile("" ::: "memory"); } while (0)
#define LGKM0 asm volatile("s_waitcnt lgkmcnt(0)" ::: "memory")
#define WVM(n) asm volatile("s_waitcnt vmcnt(" #n ")" ::: "memory")

// -------- fused preproc: cvt x->bf16 | transpose Win | transpose Wout --------
__global__ __launch_bounds__(256) void preproc_kernel(
    const float* __restrict__ x, __hip_bfloat16* __restrict__ xb,
    const float* __restrict__ Win, __hip_bfloat16* __restrict__ WinT,
    const float* __restrict__ Wout, __hip_bfloat16* __restrict__ WoutT) {
  __shared__ float tile[32][33];
  const int b = blockIdx.x;
  const int tid = threadIdx.x;
  if (b < 8192) {  // cvt: 8192x1024 f32 -> bf16, 4 elems/thread
    int idx = (b * 256 + tid) * 4;
    float4 v = *reinterpret_cast<const float4*>(x + idx);
    union { short4 s4; __hip_bfloat16 h[4]; } u;
    u.h[0] = __float2bfloat16(v.x);
    u.h[1] = __float2bfloat16(v.y);
    u.h[2] = __float2bfloat16(v.z);
    u.h[3] = __float2bfloat16(v.w);
    *reinterpret_cast<short4*>(xb + idx) = u.s4;
    return;
  }
  const float* in;  __hip_bfloat16* out;  int R, C, tb;
  if (b < 8192 + 2048) { tb = b - 8192;  in = Win;  out = WinT;  R = 1024; C = 2048; }
  else                 { tb = b - 10240; in = Wout; out = WoutT; R = 2048; C = 1024; }
  const int nbx = C / 32;
  const int c0 = (tb % nbx) * 32, r0 = (tb / nbx) * 32;
  const int tx = tid & 31, ty = tid >> 5;  // 32x8
#pragma unroll
  for (int j = 0; j < 32; j += 8)
    tile[ty + j][tx] = in[(size_t)(r0 + ty + j) * C + c0 + tx];
  __syncthreads();
#pragma unroll
  for (int j = 0; j < 32; j += 8)
    out[(size_t)(c0 + ty + j) * R + r0 + tx] = __float2bfloat16(tile[tx][ty + j]);
}

// ---------------- GEMM1: 256x256 4-phase/K-tile schedule (R9/R15 verbatim) -------
// C = silu(A[M,K] @ Bt[N,K]^T + bias) -> bf16.  512 thr (8 waves, 2M x 4N),
// per-wave 128x64 out. BK=64. Unit = [256 rows][32 K] bf16 = 16KB; LDS = 128KB.
__global__ __launch_bounds__(512, 1) void gemm8p4_kernel(
    const __hip_bfloat16* __restrict__ A,
    const __hip_bfloat16* __restrict__ Bt,
    const float* __restrict__ bias,
    __hip_bfloat16* __restrict__ Cout,
    int M, int N, int K) {
  constexpr int AUNIT = 16384;
  constexpr int BOFF = 4 * AUNIT;  // A region 64KB, B region 64KB
  __shared__ int4 ldsv[(8 * AUNIT) / 16];  // 128KB
  char* lds = (char*)ldsv;

  const int tid = threadIdx.x;
  const int l = tid & 63;
  const int w = tid >> 6;
  const int wm = w >> 2, wn = w & 3;         // 2(M) x 4(N); per-wave 128x64
  const int fr = l & 15;
  const int sl = ((l >> 4) ^ ((fr >> 3) << 1)) * 16;  // st_16x32 swizzled slot
  const int arowb = (wm * 128 + fr) * 64 + sl;        // byte in 16KB A unit
  const int browb = (wn * 64 + fr) * 64 + sl;         // byte in 16KB B unit

  const int nbn = N >> 8;
  int bid = blockIdx.x;
  const int cpx = gridDim.x >> 3;            // XCD chunking; grid % 8 == 0
  bid = (bid & 7) * cpx + (bid >> 3);
  const int brow = (bid / nbn) * 256;
  const int bcol = (bid % nbn) * 256;
  const size_t K2 = (size_t)K * 2;

  int ar[2], acb[2], dst[2];
#pragma unroll
  for (int j = 0; j < 2; ++j) {
    int d = j * 8192 + w * 1024 + l * 16;
    int lg = d ^ (((d >> 9) & 1) << 5);
    ar[j] = lg >> 6;  acb[j] = lg & 63;
    dst[j] = j * 8192 + w * 1024;
  }

  const char* Abp = (const char*)A;
  const char* Bbp = (const char*)Bt;

  auto stA = [&](int t, int kk) {
    const int base = ((t & 1) * 2 + kk) * AUNIT;
#pragma unroll
    for (int j = 0; j < 2; ++j)
      gload16(Abp + (size_t)(brow + ar[j]) * K2 + (size_t)t * 128 + kk * 64 + acb[j],
              lds + base + dst[j]);
  };
  auto stB = [&](int t, int kk) {
    const int base = BOFF + ((t & 1) * 2 + kk) * AUNIT;
#pragma unroll
    for (int j = 0; j < 2; ++j)
      gload16(Bbp + (size_t)(bcol + ar[j]) * K2 + (size_t)t * 128 + kk * 64 + acb[j],
              lds + base + dst[j]);
  };

  f32x4 acc[8][4];
#pragma unroll
  for (int m = 0; m < 8; ++m)
#pragma unroll
    for (int n = 0; n < 4; ++n) acc[m][n] = (f32x4)0.f;

  short8_t af[4], bf[4];
  auto rdA4 = [&](int t, int kk, int mh) {
    const int base = ((t & 1) * 2 + kk) * AUNIT + arowb + mh * 4096;
#pragma unroll
    for (int j = 0; j < 4; ++j)
      af[j] = *(const short8_t*)(lds + base + j * 1024);
  };
  auto rdB4 = [&](int t, int kk) {
    const int base = BOFF + ((t & 1) * 2 + kk) * AUNIT + browb;
#pragma unroll
    for (int j = 0; j < 4; ++j)
      bf[j] = *(const short8_t*)(lds + base + j * 1024);
  };
  auto mm0 = [&]() {
    __builtin_amdgcn_s_setprio(1);
#pragma unroll
    for (int j = 0; j < 4; ++j)
#pragma unroll
      for (int n = 0; n < 4; ++n)
        acc[j][n] = __builtin_amdgcn_mfma_f32_16x16x32_bf16(af[j], bf[n], acc[j][n], 0, 0, 0);
    __builtin_amdgcn_s_setprio(0);
  };
  auto mm1 = [&]() {
    __builtin_amdgcn_s_setprio(1);
#pragma unroll
    for (int j = 0; j < 4; ++j)
#pragma unroll
      for (int n = 0; n < 4; ++n)
        acc[4 + j][n] = __builtin_amdgcn_mfma_f32_16x16x32_bf16(af[j], bf[n], acc[4 + j][n], 0, 0, 0);
    __builtin_amdgcn_s_setprio(0);
  };

  const int NT = K >> 6;  // BK=64; NT >= 3
  stA(0, 0); stB(0, 0); stA(0, 1); stB(0, 1); stA(1, 0); stB(1, 0);
  WVM(8); BARRIER();

  for (int T = 0; T < NT - 2; ++T) {
    rdA4(T, 0, 0); rdB4(T, 0); stA(T + 1, 1);
    BARRIER(); LGKM0; mm0(); BARRIER();
    rdA4(T, 0, 1);             stB(T + 1, 1);
    BARRIER(); LGKM0; mm1(); WVM(8); BARRIER();
    rdA4(T, 1, 0); rdB4(T, 1); stA(T + 2, 0);
    BARRIER(); LGKM0; mm0(); BARRIER();
    rdA4(T, 1, 1);             stB(T + 2, 0);
    BARRIER(); LGKM0; mm1(); WVM(8); BARRIER();
  }
  {
    const int T = NT - 2;
    rdA4(T, 0, 0); rdB4(T, 0); stA(T + 1, 1);
    BARRIER(); LGKM0; mm0(); BARRIER();
    rdA4(T, 0, 1);             stB(T + 1, 1);
    BARRIER(); LGKM0; mm1(); WVM(8); BARRIER();
    rdA4(T, 1, 0); rdB4(T, 1);
    BARRIER(); LGKM0; mm0(); BARRIER();
    rdA4(T, 1, 1);
    BARRIER(); LGKM0; mm1(); WVM(4); BARRIER();
  }
  {
    const int T = NT - 1;
    rdA4(T, 0, 0); rdB4(T, 0);
    BARRIER(); LGKM0; mm0(); BARRIER();
    rdA4(T, 0, 1);
    BARRIER(); LGKM0; mm1(); WVM(0); BARRIER();
    rdA4(T, 1, 0); rdB4(T, 1);
    BARRIER(); LGKM0; mm0(); BARRIER();
    rdA4(T, 1, 1);
    BARRIER(); LGKM0; mm1();
  }

  const int r0 = brow + wm * 128 + (l >> 4) * 4;
  const int c0 = bcol + wn * 64 + fr;
#pragma unroll
  for (int m = 0; m < 8; ++m) {
#pragma unroll
    for (int n = 0; n < 4; ++n) {
      const int col = c0 + n * 16;
      const float bv = bias[col];
#pragma unroll
      for (int j = 0; j < 4; ++j) {
        const int row = r0 + m * 16 + j;
        float v = acc[m][n][j] + bv;
        v = v / (1.0f + __expf(-v));
        Cout[(size_t)row * N + col] = __float2bfloat16(v);
      }
    }
  }
}

// ---------------- GEMM2: R4's gemm1b verbatim (best measured at this shape) ------
// C[M][N] = A[M,K] @ Bt[N,K]^T + bias -> f32. 256x128, BK=64, 3-buffer 144KB.
__global__ __launch_bounds__(512, 2) void gemm1b_kernel(
    const __hip_bfloat16* __restrict__ A,
    const __hip_bfloat16* __restrict__ Bt,
    const float* __restrict__ bias,
    float* __restrict__ Cout,
    int M, int N, int K) {
  constexpr int ABUF = 32768, BBUF = 16384;
  constexpr int BOFF = 3 * ABUF;
  __shared__ int4 ldsv[(3 * ABUF + 3 * BBUF) / 16];  // 144KB
  char* lds = (char*)ldsv;

  const int tid = threadIdx.x;
  const int l = tid & 63;
  const int w = tid >> 6;
  const int wm = w >> 1, wn = w & 1;
  const int fr = l & 15;
  const int sl = ((l >> 4) ^ ((fr >> 3) << 1)) * 16;
  const int arow_base = (wm * 64 + fr) * 64 + sl;
  const int brow_base = (wn * 64 + fr) * 64 + sl;

  const int nbn = N / 128;
  int bid = blockIdx.x;
  const int cpx = gridDim.x >> 3;
  bid = (bid & 7) * cpx + (bid >> 3);
  const int brow = (bid / nbn) * 256;
  const int bcol = (bid % nbn) * 128;
  const size_t K2 = (size_t)K * 2;

  int arA[2], acbA[2], dstA[2];
#pragma unroll
  for (int j = 0; j < 2; ++j) {
    int d = j * 8192 + w * 1024 + l * 16;
    int lg = d ^ (((d >> 9) & 1) << 5);
    arA[j] = lg >> 6;  acbA[j] = lg & 63;
    dstA[j] = j * 8192 + w * 1024;
  }
  int dB = w * 1024 + l * 16;
  int lgB = dB ^ (((dB >> 9) & 1) << 5);
  const int arB = lgB >> 6, acbB = lgB & 63, dstB = w * 1024;

  const char* Abp = (const char*)A;
  const char* Bbp = (const char*)Bt;

  auto stA = [&](int bufb, int kh, int tt) {
#pragma unroll
    for (int j = 0; j < 2; ++j)
      gload16(Abp + (size_t)(brow + arA[j]) * K2 + tt * 128 + kh * 64 + acbA[j],
              lds + bufb + kh * 16384 + dstA[j]);
  };
  auto stB = [&](int bufb, int kh, int tt) {
    gload16(Bbp + (size_t)(bcol + arB) * K2 + tt * 128 + kh * 64 + acbB,
            lds + BOFF + bufb / 2 + kh * 8192 + dstB);
  };

  f32x4 acc[4][4];
#pragma unroll
  for (int m = 0; m < 4; ++m)
#pragma unroll
    for (int n = 0; n < 4; ++n) acc[m][n] = (f32x4)0.f;

  const int NT = K >> 6;
  stA(0, 0, 0); stA(0, 1, 0); stB(0, 0, 0); stB(0, 1, 0);
  stA(ABUF, 0, 1); stA(ABUF, 1, 1); stB(ABUF, 0, 1); stB(ABUF, 1, 1);
  WVM(6); BARRIER();

  int curA = 0, stAb = 2 * ABUF;
  for (int T = 0; T < NT; ++T) {
    short8_t af[8], bf[8];
#pragma unroll
    for (int kh = 0; kh < 2; ++kh) {
#pragma unroll
      for (int mi = 0; mi < 4; ++mi)
        af[kh * 4 + mi] = *(const short8_t*)(lds + curA + kh * 16384 + arow_base + mi * 1024);
#pragma unroll
      for (int n = 0; n < 4; ++n)
        bf[kh * 4 + n] = *(const short8_t*)(lds + BOFF + curA / 2 + kh * 8192 + brow_base + n * 1024);
    }
    if (T + 2 < NT) {
      stA(stAb, 0, T + 2); stA(stAb, 1, T + 2);
      stB(stAb, 0, T + 2); stB(stAb, 1, T + 2);
    }
#pragma unroll
    for (int kh = 0; kh < 2; ++kh)
#pragma unroll
      for (int mi = 0; mi < 4; ++mi)
#pragma unroll
        for (int n = 0; n < 4; ++n)
          acc[mi][n] = __builtin_amdgcn_mfma_f32_16x16x32_bf16(
              af[kh * 4 + mi], bf[kh * 4 + n], acc[mi][n], 0, 0, 0);
    if (T + 1 < NT) {
      if (T + 2 < NT) { WVM(6); } else { WVM(0); }
      LGKM0;
      BARRIER();
    }
    curA += ABUF; if (curA == 3 * ABUF) curA = 0;
    stAb += ABUF; if (stAb == 3 * ABUF) stAb = 0;
  }

  const int r0 = brow + wm * 64 + (l >> 4) * 4;
  const int c0 = bcol + wn * 64 + fr;
#pragma unroll
  for (int m = 0; m < 4; ++m) {
#pragma unroll
    for (int n = 0; n < 4; ++n) {
      const int col = c0 + n * 16;
      const float bv = bias[col];
#pragma unroll
      for (int j = 0; j < 4; ++j) {
        const int row = r0 + m * 16 + j;
        Cout[(size_t)row * N + col] = acc[m][n][j] + bv;
      }
    }
  }
}

// ---------------- EMA scan: y = cb_i * g + Dp_i * xi ----------------
__global__ __launch_bounds__(256) void scan_kernel(
    const __hip_bfloat16* __restrict__ xi,  // [B*L, DI]
    const float* __restrict__ Bp,           // [DI, DS]
    const float* __restrict__ Cp,           // [DS, DI]
    const float* __restrict__ Dp,           // [DI]
    __hip_bfloat16* __restrict__ y) {
  constexpr int L = 2048, DI = 2048, DS = 16, TW = 256, H = 32;
  const int tid = threadIdx.x;
  const int bidx = blockIdx.x;
  const int iblk = bidx & 7;
  const int chunk = (bidx >> 3) & 7;
  const int b = bidx >> 6;
  const int i = iblk * 256 + tid;

  float cb = 0.f;
#pragma unroll
  for (int s = 0; s < DS; ++s) cb += Bp[i * DS + s] * Cp[s * DI + i];
  const float dp = Dp[i];

  const int t0 = chunk * TW;
  int tstart = t0 - H;
  if (tstart < 0) tstart = 0;

  const __hip_bfloat16* xp = xi + (size_t)(b * L) * DI + i;
  __hip_bfloat16* yp = y + (size_t)(b * L) * DI + i;

  float g = 0.f;
  const __hip_bfloat16* p = xp + (size_t)tstart * DI;
  for (int t = tstart; t < t0; ++t, p += DI)
    g = g * 0.9f + __bfloat162float(*p);
  __hip_bfloat16* q = yp + (size_t)t0 * DI;
  for (int t = 0; t < TW; ++t, p += DI, q += DI) {
    float xv = __bfloat162float(*p);
    g = g * 0.9f + xv;
    *q = __float2bfloat16(cb * g + dp * xv);
  }
}

extern "C" void kernel_launch(void* const* d_in, const int* in_sizes, int n_in,
                              void* d_out, int out_size, void* d_ws, size_t ws_size,
                              hipStream_t stream) {
  const float* x    = (const float*)d_in[0];
  const float* Win  = (const float*)d_in[1];
  const float* bin  = (const float*)d_in[2];
  const float* Bp   = (const float*)d_in[3];
  const float* Cp   = (const float*)d_in[4];
  const float* Dp   = (const float*)d_in[5];
  const float* Wout = (const float*)d_in[6];
  const float* bout = (const float*)d_in[7];
  float* out = (float*)d_out;

  constexpr int Bb = 4, L = 2048, DM = 1024, DI = 2048;
  constexpr int Mrows = Bb * L;  // 8192

  char* ws = (char*)d_ws;
  __hip_bfloat16* xb    = (__hip_bfloat16*)ws;                           // 16 MB
  __hip_bfloat16* WinT  = (__hip_bfloat16*)(ws + (16u << 20));           // 4 MB
  __hip_bfloat16* WoutT = (__hip_bfloat16*)(ws + (20u << 20));           // 4 MB
  __hip_bfloat16* xi    = (__hip_bfloat16*)(ws + (24u << 20));           // 32 MB
  __hip_bfloat16* yb    = (__hip_bfloat16*)(ws + (56u << 20));           // 32 MB

  // 1. fused preproc: x->bf16 (8192 blocks) | Win^T (2048) | Wout^T (2048)
  preproc_kernel<<<8192 + 2048 + 2048, 256, 0, stream>>>(
      x, xb, Win, WinT, Wout, WoutT);
  // 2. xi = silu(xb @ WinT^T + bin)  [8192,2048] bf16. 256^2 tiles, grid 32x8=256.
  gemm8p4_kernel<<<(Mrows / 256) * (DI / 256), 512, 0, stream>>>(
      xb, WinT, bin, xi, Mrows, DI, DM);
  // 3. EMA scan -> y bf16
  scan_kernel<<<Bb * (L / 256) * (DI / 256), 256, 0, stream>>>(xi, Bp, Cp, Dp, yb);
  // 4. out = yb @ WoutT^T + bout  [8192,1024] f32. grid 32x8=256 (R4 config).
  gemm1b_kernel<<<(Mrows / 256) * (DM / 128), 512, 0, stream>>>(
      yb, WoutT, bout, out, Mrows, DM, DI);
}